// Round 1
// baseline (358.076 us; speedup 1.0000x reference)
//
#include <hip/hip_runtime.h>

// VQ-VAE nearest-codeword + loss.
// feature: [8192, 512] fp32 -> rows f: [32768, 128]
// W: [2048, 128] fp32
// d_out: loss[8192] fp32, then out[32768*128] fp32 (= [8192,512])

#define NROWS 32768
#define DIM   128
#define NCODE 2048
#define BM    64     // rows per block
#define BN    128    // codes per iteration
#define BK    32     // dims per LDS chunk of W
#define LDF   132    // padded f-tile leading dim (floats)
#define LDW   36     // padded w-chunk leading dim (floats)

__global__ __launch_bounds__(256)
void wsq_kernel(const float* __restrict__ W, float* __restrict__ wsq) {
    // 4 waves per block, one code per wave. grid = 2048/4 = 512
    const int wv   = threadIdx.x >> 6;
    const int lane = threadIdx.x & 63;
    const int code = blockIdx.x * 4 + wv;
    float2 v = *(const float2*)(W + (size_t)code * DIM + lane * 2);
    float p = v.x * v.x + v.y * v.y;
    #pragma unroll
    for (int m = 1; m < 64; m <<= 1) p += __shfl_xor(p, m, 64);
    if (lane == 0) wsq[code] = p;
}

__global__ __launch_bounds__(256, 3)
void vq_main(const float* __restrict__ feature, const float* __restrict__ W,
             const float* __restrict__ wsq, float* __restrict__ out) {
    __shared__ float lds_f[BM * LDF];
    __shared__ float lds_w[BN * LDW];
    __shared__ float dl[BM];
    __shared__ int   jl[BM];

    const int tid = threadIdx.x;
    const int tx  = tid & 15;   // code lane
    const int ty  = tid >> 4;   // row group
    const int rb  = blockIdx.x; // 512 blocks of 64 rows

    // ---- stage f tile (64 x 128), coalesced float4 ----
    {
        const float* fbase = feature + (size_t)rb * BM * DIM;
        #pragma unroll
        for (int t = 0; t < 8; ++t) {
            int f4   = tid + t * 256;         // 0..2047
            int row  = f4 >> 5;               // 32 float4 per row
            int dcol = (f4 & 31) << 2;
            float4 v = *(const float4*)(fbase + (size_t)f4 * 4);
            *(float4*)&lds_f[row * LDF + dcol] = v;
        }
    }

    float run_s[4];
    int   run_j[4];
    #pragma unroll
    for (int rr = 0; rr < 4; ++rr) { run_s[rr] = 3.4e38f; run_j[rr] = 0; }

    for (int cb = 0; cb < NCODE / BN; ++cb) {
        float acc[4][8];
        #pragma unroll
        for (int rr = 0; rr < 4; ++rr)
            #pragma unroll
            for (int cc = 0; cc < 8; ++cc) acc[rr][cc] = 0.0f;

        for (int dc = 0; dc < DIM / BK; ++dc) {
            __syncthreads();  // prior reads of lds_w done (also orders f-tile writes)
            // stage W chunk: 128 codes x 32 dims = 1024 float4 / 256 threads
            {
                #pragma unroll
                for (int t = 0; t < 4; ++t) {
                    int f4  = tid + t * 256;  // 0..1023
                    int c   = f4 >> 3;        // 8 float4 per code-chunk
                    int dd4 = (f4 & 7) << 2;
                    float4 v = *(const float4*)(W + ((size_t)(cb * BN + c)) * DIM + dc * BK + dd4);
                    *(float4*)&lds_w[c * LDW + dd4] = v;
                }
            }
            __syncthreads();  // lds_w visible

            #pragma unroll
            for (int dd = 0; dd < BK; dd += 4) {
                float4 fa[4];
                #pragma unroll
                for (int rr = 0; rr < 4; ++rr)
                    fa[rr] = *(const float4*)&lds_f[(ty * 4 + rr) * LDF + dc * BK + dd];
                float4 wb[8];
                #pragma unroll
                for (int cc = 0; cc < 8; ++cc)
                    wb[cc] = *(const float4*)&lds_w[(cc * 16 + tx) * LDW + dd];
                #pragma unroll
                for (int rr = 0; rr < 4; ++rr) {
                    #pragma unroll
                    for (int cc = 0; cc < 8; ++cc) {
                        float a = acc[rr][cc];
                        a = fmaf(fa[rr].x, wb[cc].x, a);
                        a = fmaf(fa[rr].y, wb[cc].y, a);
                        a = fmaf(fa[rr].z, wb[cc].z, a);
                        a = fmaf(fa[rr].w, wb[cc].w, a);
                        acc[rr][cc] = a;
                    }
                }
            }
        }

        // ---- scoring: s = wsq - 2*dot; min over this 128-code block ----
        float ws8[8];
        #pragma unroll
        for (int cc = 0; cc < 8; ++cc) ws8[cc] = wsq[cb * BN + cc * 16 + tx];

        #pragma unroll
        for (int rr = 0; rr < 4; ++rr) {
            float bs = 3.4e38f; int bj = 0x7fffffff;
            #pragma unroll
            for (int cc = 0; cc < 8; ++cc) {
                int   code = cb * BN + cc * 16 + tx;
                float s    = ws8[cc] - 2.0f * acc[rr][cc];
                if (s < bs) { bs = s; bj = code; }  // codes ascend with cc -> first-index tie-break
            }
            #pragma unroll
            for (int m = 1; m < 16; m <<= 1) {
                float os = __shfl_xor(bs, m, 64);
                int   oj = __shfl_xor(bj, m, 64);
                if (os < bs || (os == bs && oj < bj)) { bs = os; bj = oj; }
            }
            if (bs < run_s[rr] || (bs == run_s[rr] && bj < run_j[rr])) {
                run_s[rr] = bs; run_j[rr] = bj;
            }
        }
    }

    // ---- epilogue ----
    if (tx == 0) {
        #pragma unroll
        for (int rr = 0; rr < 4; ++rr) {
            dl[ty * 4 + rr] = run_s[rr];
            jl[ty * 4 + rr] = run_j[rr];
        }
    }
    __syncthreads();

    // f_sq per row: 4 threads per row, 32 dims each, then shuffle-combine
    const int row = tid >> 2;
    const int q   = tid & 3;
    {
        float p = 0.0f;
        const float* fr = &lds_f[row * LDF + q * 32];
        #pragma unroll
        for (int k8 = 0; k8 < 8; ++k8) {
            float4 v = *(const float4*)&fr[k8 * 4];
            p = fmaf(v.x, v.x, p); p = fmaf(v.y, v.y, p);
            p = fmaf(v.z, v.z, p); p = fmaf(v.w, v.w, p);
        }
        p += __shfl_xor(p, 1, 64);
        p += __shfl_xor(p, 2, 64);
        if (q == 0) dl[row] += p;   // dl[row] = f_sq + s_min = min squared distance
    }
    __syncthreads();

    // loss: 16 batch rows per block (64 rows / 4 slots)
    if (tid < 16) {
        float s = dl[tid * 4] + dl[tid * 4 + 1] + dl[tid * 4 + 2] + dl[tid * 4 + 3];
        out[(size_t)rb * 16 + tid] = 0.3125f * s;  // 1.25 / 4
    }

    // gather out rows: 4 threads per row copy W[j]
    {
        int j = jl[row];
        const float4* src = (const float4*)(W + (size_t)j * DIM + q * 32);
        float4* dst = (float4*)(out + 8192 + ((size_t)(rb * BM + row)) * DIM + q * 32);
        #pragma unroll
        for (int k8 = 0; k8 < 8; ++k8) dst[k8] = src[k8];
    }
}

extern "C" void kernel_launch(void* const* d_in, const int* in_sizes, int n_in,
                              void* d_out, int out_size, void* d_ws, size_t ws_size,
                              hipStream_t stream) {
    const float* feature = (const float*)d_in[0];
    const float* W       = (const float*)d_in[1];
    float*       out     = (float*)d_out;
    float*       wsq     = (float*)d_ws;  // 2048 floats

    wsq_kernel<<<512, 256, 0, stream>>>(W, wsq);
    vq_main<<<512, 256, 0, stream>>>(feature, W, wsq, out);
}

// Round 4
// 219.837 us; speedup vs baseline: 1.6288x; 1.6288x over previous
//
#include <hip/hip_runtime.h>
#include <float.h>

// VQ-VAE nearest-codeword + loss, bf16x2-emulated fp32 GEMM on MFMA.
// feature: [8192, 512] fp32 -> rows f: [32768, 128]
// W: [2048, 128] fp32
// d_out: loss[8192] fp32, then out[32768*128] fp32
// Staging: reg-staged double buffer (global->reg->ds_write), NO global_load_lds.

#define NROWS 32768
#define DIM   128
#define NCODE 2048
#define BM    128            // rows per block  -> grid 256 = 1 block/CU
#define CB    128            // codes per main-loop iteration
#define NITER (NCODE / CB)   // 16
#define TAU   0.02f          // rescore threshold (error bound ~2e-3)

typedef __attribute__((ext_vector_type(8))) short short8v;  // 8 bf16 (4 VGPR)
typedef __attribute__((ext_vector_type(4))) float f32x4;

static __device__ __forceinline__ unsigned short f2bf_rne(float x) {
    unsigned u = __float_as_uint(x);
    unsigned r = u + 0x7FFFu + ((u >> 16) & 1u);
    return (unsigned short)(r >> 16);
}
static __device__ __forceinline__ float bf2f(unsigned short h) {
    return __uint_as_float(((unsigned)h) << 16);
}

// ---------------- prep: W fp32 -> frag-major bf16 hi/lo + wsq ----------------
// ws layout (shorts): whi[tile][kc][g][c][8], strides tile:2048 kc:512 g:128 c:8
// value = bf16(W[tile*16+c][kc*32+g*8+e])
__global__ __launch_bounds__(256)
void vq_prep(const float* __restrict__ W, short* __restrict__ whi,
             short* __restrict__ wlo, float* __restrict__ wsq) {
    const int t    = blockIdx.x * 256 + threadIdx.x;  // 8192 threads
    const int code = t >> 2;
    const int kc   = t & 3;
    const float* src = W + (size_t)code * DIM + kc * 32;

    float4 v[8];
    #pragma unroll
    for (int i = 0; i < 8; ++i) v[i] = *(const float4*)(src + i * 4);

    float p = 0.0f;
    #pragma unroll
    for (int i = 0; i < 8; ++i) {
        p = fmaf(v[i].x, v[i].x, p); p = fmaf(v[i].y, v[i].y, p);
        p = fmaf(v[i].z, v[i].z, p); p = fmaf(v[i].w, v[i].w, p);
    }
    p += __shfl_xor(p, 1, 64);
    p += __shfl_xor(p, 2, 64);
    if (kc == 0) wsq[code] = p;

    const int tile = code >> 4;
    const int c    = code & 15;
    const size_t off = (size_t)tile * 2048 + (size_t)kc * 512 + (size_t)c * 8;
    #pragma unroll
    for (int g = 0; g < 4; ++g) {
        float xs[8] = { v[2*g].x, v[2*g].y, v[2*g].z, v[2*g].w,
                        v[2*g+1].x, v[2*g+1].y, v[2*g+1].z, v[2*g+1].w };
        short8v hi, lo;
        #pragma unroll
        for (int e = 0; e < 8; ++e) {
            unsigned short hb = f2bf_rne(xs[e]);
            float rem = xs[e] - bf2f(hb);
            unsigned short lb = f2bf_rne(rem);
            hi[e] = (short)hb; lo[e] = (short)lb;
        }
        *(short8v*)(whi + off + g * 128) = hi;
        *(short8v*)(wlo + off + g * 128) = lo;
    }
}

// ---------------- main MFMA kernel ----------------
__global__ __launch_bounds__(256, 1)
void vq_mfma(const float* __restrict__ feature, const float* __restrict__ W,
             const short* __restrict__ whi, const short* __restrict__ wlo,
             const float* __restrict__ wsqg, float* __restrict__ out) {
    __shared__ short lds_w[2][2][16384];   // [buf][hi/lo][32KB of shorts] = 128KB
    __shared__ float dist_l[BM];
    __shared__ int   j_l[BM];
    __shared__ float fsq_l[BM];
    __shared__ int   flags[132];           // [0]=count, then row list
    __shared__ float frow[DIM];
    __shared__ float rbest[4];
    __shared__ int   rbj[4];

    const int tid  = threadIdx.x;
    const int lane = tid & 63;
    const int w    = tid >> 6;     // wave 0..3
    const int c    = lane & 15;    // col / code-local
    const int g    = lane >> 4;    // k-group / row-group
    const int rb   = blockIdx.x;   // 256 blocks of 128 rows

    if (tid == 0) flags[0] = 0;

    short8v stg_h[8], stg_l[8];

    // ---- prologue: issue loads for cb=0 ----
    {
        const short8v* sh = (const short8v*)(whi + (size_t)tid * 8);
        const short8v* sl = (const short8v*)(wlo + (size_t)tid * 8);
        #pragma unroll
        for (int i = 0; i < 8; ++i) { stg_h[i] = sh[i * 256]; stg_l[i] = sl[i * 256]; }
    }

    // ---- load f rows, split to bf16 hi/lo A-fragments (in registers) ----
    // A-frag layout (16x16x32): lane holds A[row=c][k = kc*32 + g*8 + e]
    short8v Ahi[2][4], Alo[2][4];
    #pragma unroll
    for (int rf = 0; rf < 2; ++rf) {
        const int row = rb * BM + w * 32 + rf * 16 + c;
        const float* fp = feature + (size_t)row * DIM + g * 8;
        float fs = 0.0f;
        #pragma unroll
        for (int kc = 0; kc < 4; ++kc) {
            float4 u0 = *(const float4*)(fp + kc * 32);
            float4 u1 = *(const float4*)(fp + kc * 32 + 4);
            float xs[8] = { u0.x, u0.y, u0.z, u0.w, u1.x, u1.y, u1.z, u1.w };
            short8v hi, lo;
            #pragma unroll
            for (int e = 0; e < 8; ++e) {
                unsigned short hb = f2bf_rne(xs[e]);
                float rem = xs[e] - bf2f(hb);
                unsigned short lb = f2bf_rne(rem);
                hi[e] = (short)hb; lo[e] = (short)lb;
                fs = fmaf(xs[e], xs[e], fs);
            }
            Ahi[rf][kc] = hi; Alo[rf][kc] = lo;
        }
        // combine partial f_sq over the 4 g-groups of this row
        fs += __shfl_xor(fs, 16, 64);
        fs += __shfl_xor(fs, 32, 64);
        if (g == 0) fsq_l[w * 32 + rf * 16 + c] = fs;
    }

    // ---- prologue: write cb=0 into buf 0 ----
    #pragma unroll
    for (int i = 0; i < 8; ++i)
        *(short8v*)&lds_w[0][0][tid * 8 + i * 2048] = stg_h[i];
    #pragma unroll
    for (int i = 0; i < 8; ++i)
        *(short8v*)&lds_w[0][1][tid * 8 + i * 2048] = stg_l[i];

    // top-2 trackers per lane: rows (g*4+q) of each row-frag, code c of each tile
    float s1[2][4], s2[2][4];
    int   j1[2][4];
    #pragma unroll
    for (int rf = 0; rf < 2; ++rf)
        #pragma unroll
        for (int q = 0; q < 4; ++q) { s1[rf][q] = FLT_MAX; s2[rf][q] = FLT_MAX; j1[rf][q] = NCODE; }

    __syncthreads();  // buf0 ready

    for (int cb = 0; cb < NITER; ++cb) {
        const int  buf = cb & 1;
        const bool pre = (cb + 1 < NITER);
        if (pre) {  // issue next chunk's global loads early (latency hides under MFMA)
            const short8v* sh = (const short8v*)(whi + (size_t)(cb + 1) * 16384 + (size_t)tid * 8);
            const short8v* sl = (const short8v*)(wlo + (size_t)(cb + 1) * 16384 + (size_t)tid * 8);
            #pragma unroll
            for (int i = 0; i < 8; ++i) { stg_h[i] = sh[i * 256]; stg_l[i] = sl[i * 256]; }
        }

        const short* bh = &lds_w[buf][0][0];
        const short* bl = &lds_w[buf][1][0];

        // prefetch wsq for this chunk's 8 tiles (one 64B line each, L1-resident)
        float wq8[8];
        #pragma unroll
        for (int t = 0; t < CB / 16; ++t) wq8[t] = wsqg[cb * CB + t * 16 + c];

        #pragma unroll
        for (int t = 0; t < CB / 16; ++t) {
            short8v Bh[4], Bl[4];
            #pragma unroll
            for (int kc = 0; kc < 4; ++kc) {
                Bh[kc] = *(const short8v*)(bh + t * 2048 + kc * 512 + lane * 8);
                Bl[kc] = *(const short8v*)(bl + t * 2048 + kc * 512 + lane * 8);
            }
            const int codebase = cb * CB + t * 16 + c;

            #pragma unroll
            for (int rf = 0; rf < 2; ++rf) {
                f32x4 acc = {0.f, 0.f, 0.f, 0.f};
                #pragma unroll
                for (int kc = 0; kc < 4; ++kc)
                    acc = __builtin_amdgcn_mfma_f32_16x16x32_bf16(Ahi[rf][kc], Bh[kc], acc, 0, 0, 0);
                #pragma unroll
                for (int kc = 0; kc < 4; ++kc)
                    acc = __builtin_amdgcn_mfma_f32_16x16x32_bf16(Ahi[rf][kc], Bl[kc], acc, 0, 0, 0);
                #pragma unroll
                for (int kc = 0; kc < 4; ++kc)
                    acc = __builtin_amdgcn_mfma_f32_16x16x32_bf16(Alo[rf][kc], Bh[kc], acc, 0, 0, 0);
                #pragma unroll
                for (int q = 0; q < 4; ++q) {
                    float s  = fmaf(-2.0f, acc[q], wq8[t]);
                    bool  lt = s < s1[rf][q];
                    s2[rf][q] = fminf(s2[rf][q], lt ? s1[rf][q] : s);
                    j1[rf][q] = lt ? codebase : j1[rf][q];
                    s1[rf][q] = lt ? s : s1[rf][q];
                }
            }
        }

        if (pre) {  // write next chunk into the other buffer (safe: it was last read in cb-1)
            #pragma unroll
            for (int i = 0; i < 8; ++i)
                *(short8v*)&lds_w[buf ^ 1][0][tid * 8 + i * 2048] = stg_h[i];
            #pragma unroll
            for (int i = 0; i < 8; ++i)
                *(short8v*)&lds_w[buf ^ 1][1][tid * 8 + i * 2048] = stg_l[i];
        }
        __syncthreads();
    }

    // ---- cross-lane top-2 merge over the 16 code-lanes (xor 1,2,4,8 flip c) ----
    #pragma unroll
    for (int rf = 0; rf < 2; ++rf) {
        #pragma unroll
        for (int q = 0; q < 4; ++q) {
            float a1 = s1[rf][q]; int aj = j1[rf][q]; float a2 = s2[rf][q];
            #pragma unroll
            for (int m = 1; m < 16; m <<= 1) {
                float b1 = __shfl_xor(a1, m, 64);
                int   bj = __shfl_xor(aj, m, 64);
                float b2 = __shfl_xor(a2, m, 64);
                bool swap = (b1 < a1) || (b1 == a1 && bj < aj);
                float other1 = swap ? a1 : b1;
                a2 = fminf(fminf(a2, b2), other1);
                a1 = swap ? b1 : a1;
                aj = swap ? bj : aj;
            }
            if (c == 0) {
                const int row = w * 32 + rf * 16 + g * 4 + q;
                dist_l[row] = a1;
                j_l[row]    = aj;
                if (a2 - a1 < TAU) {
                    int idx = atomicAdd(&flags[0], 1);
                    flags[1 + idx] = row;
                }
            }
        }
    }
    __syncthreads();

    // ---- exact fp32 rescore for flagged rows (rare) ----
    const int nf = flags[0];
    for (int i = 0; i < nf; ++i) {
        const int row = flags[1 + i];
        if (tid < 32) {
            float4 v = *(const float4*)(feature + ((size_t)(rb * BM + row)) * DIM + tid * 4);
            *(float4*)&frow[tid * 4] = v;
        }
        __syncthreads();
        float best = FLT_MAX; int bj = NCODE;
        #pragma unroll 1
        for (int cc = 0; cc < 8; ++cc) {
            const int code = tid * 8 + cc;
            const float* wp = W + (size_t)code * DIM;
            float d = 0.0f;
            #pragma unroll
            for (int k = 0; k < DIM; k += 4) {
                float4 wv = *(const float4*)(wp + k);
                d = fmaf(wv.x, frow[k],     d);
                d = fmaf(wv.y, frow[k + 1], d);
                d = fmaf(wv.z, frow[k + 2], d);
                d = fmaf(wv.w, frow[k + 3], d);
            }
            float s = wsqg[code] - 2.0f * d;
            if (s < best) { best = s; bj = code; }
        }
        #pragma unroll
        for (int m = 1; m < 64; m <<= 1) {
            float ob = __shfl_xor(best, m, 64);
            int   oj = __shfl_xor(bj, m, 64);
            if (ob < best || (ob == best && oj < bj)) { best = ob; bj = oj; }
        }
        if (lane == 0) { rbest[w] = best; rbj[w] = bj; }
        __syncthreads();
        if (tid == 0) {
            float bb = rbest[0]; int jj = rbj[0];
            #pragma unroll
            for (int ww = 1; ww < 4; ++ww) {
                if (rbest[ww] < bb || (rbest[ww] == bb && rbj[ww] < jj)) { bb = rbest[ww]; jj = rbj[ww]; }
            }
            dist_l[row] = bb; j_l[row] = jj;
        }
        __syncthreads();
    }

    // ---- loss: 32 batch rows per block ----
    if (tid < 32) {
        float s = 0.0f;
        #pragma unroll
        for (int sl = 0; sl < 4; ++sl) {
            int r = tid * 4 + sl;
            s += dist_l[r] + fsq_l[r];
        }
        out[(size_t)rb * 32 + tid] = 0.3125f * s;  // 1.25 / 4
    }

    // ---- gather out rows: 2 threads per row ----
    {
        const int row  = tid >> 1;
        const int half = tid & 1;
        const int j    = j_l[row];
        const float4* src = (const float4*)(W + (size_t)j * DIM + half * 64);
        float4* dst = (float4*)(out + 8192 + ((size_t)(rb * BM + row)) * DIM + half * 64);
        #pragma unroll
        for (int q2 = 0; q2 < 16; ++q2) dst[q2] = src[q2];
    }
}

// ---------------- fallback (round-1 fp32 VALU path, used if ws too small) ----------------
#define F_BM  64
#define F_BN  128
#define F_BK  32
#define F_LDF 132
#define F_LDW 36

__global__ __launch_bounds__(256)
void wsq_kernel(const float* __restrict__ W, float* __restrict__ wsq) {
    const int wv   = threadIdx.x >> 6;
    const int lane = threadIdx.x & 63;
    const int code = blockIdx.x * 4 + wv;
    float2 v = *(const float2*)(W + (size_t)code * DIM + lane * 2);
    float p = v.x * v.x + v.y * v.y;
    #pragma unroll
    for (int m = 1; m < 64; m <<= 1) p += __shfl_xor(p, m, 64);
    if (lane == 0) wsq[code] = p;
}

__global__ __launch_bounds__(256, 3)
void vq_main(const float* __restrict__ feature, const float* __restrict__ W,
             const float* __restrict__ wsq, float* __restrict__ out) {
    __shared__ float lds_f[F_BM * F_LDF];
    __shared__ float lds_w[F_BN * F_LDW];
    __shared__ float dl[F_BM];
    __shared__ int   jl[F_BM];

    const int tid = threadIdx.x;
    const int tx  = tid & 15;
    const int ty  = tid >> 4;
    const int rbk = blockIdx.x;

    {
        const float* fbase = feature + (size_t)rbk * F_BM * DIM;
        #pragma unroll
        for (int t = 0; t < 8; ++t) {
            int f4 = tid + t * 256;
            int row = f4 >> 5, dcol = (f4 & 31) << 2;
            float4 v = *(const float4*)(fbase + (size_t)f4 * 4);
            *(float4*)&lds_f[row * F_LDF + dcol] = v;
        }
    }

    float run_s[4]; int run_j[4];
    #pragma unroll
    for (int rr = 0; rr < 4; ++rr) { run_s[rr] = 3.4e38f; run_j[rr] = 0; }

    for (int cb = 0; cb < NCODE / F_BN; ++cb) {
        float acc[4][8];
        #pragma unroll
        for (int rr = 0; rr < 4; ++rr)
            #pragma unroll
            for (int cc = 0; cc < 8; ++cc) acc[rr][cc] = 0.0f;

        for (int dc = 0; dc < DIM / F_BK; ++dc) {
            __syncthreads();
            #pragma unroll
            for (int t = 0; t < 4; ++t) {
                int f4 = tid + t * 256;
                int cx = f4 >> 3, dd4 = (f4 & 7) << 2;
                float4 v = *(const float4*)(W + ((size_t)(cb * F_BN + cx)) * DIM + dc * F_BK + dd4);
                *(float4*)&lds_w[cx * F_LDW + dd4] = v;
            }
            __syncthreads();

            #pragma unroll
            for (int dd = 0; dd < F_BK; dd += 4) {
                float4 fa[4];
                #pragma unroll
                for (int rr = 0; rr < 4; ++rr)
                    fa[rr] = *(const float4*)&lds_f[(ty * 4 + rr) * F_LDF + dc * F_BK + dd];
                float4 wb[8];
                #pragma unroll
                for (int cc = 0; cc < 8; ++cc)
                    wb[cc] = *(const float4*)&lds_w[(cc * 16 + tx) * F_LDW + dd];
                #pragma unroll
                for (int rr = 0; rr < 4; ++rr)
                    #pragma unroll
                    for (int cc = 0; cc < 8; ++cc) {
                        float a = acc[rr][cc];
                        a = fmaf(fa[rr].x, wb[cc].x, a);
                        a = fmaf(fa[rr].y, wb[cc].y, a);
                        a = fmaf(fa[rr].z, wb[cc].z, a);
                        a = fmaf(fa[rr].w, wb[cc].w, a);
                        acc[rr][cc] = a;
                    }
            }
        }

        float ws8[8];
        #pragma unroll
        for (int cc = 0; cc < 8; ++cc) ws8[cc] = wsq[cb * F_BN + cc * 16 + tx];

        #pragma unroll
        for (int rr = 0; rr < 4; ++rr) {
            float bs = 3.4e38f; int bj = 0x7fffffff;
            #pragma unroll
            for (int cc = 0; cc < 8; ++cc) {
                int code = cb * F_BN + cc * 16 + tx;
                float s = ws8[cc] - 2.0f * acc[rr][cc];
                if (s < bs) { bs = s; bj = code; }
            }
            #pragma unroll
            for (int m = 1; m < 16; m <<= 1) {
                float os = __shfl_xor(bs, m, 64);
                int   oj = __shfl_xor(bj, m, 64);
                if (os < bs || (os == bs && oj < bj)) { bs = os; bj = oj; }
            }
            if (bs < run_s[rr] || (bs == run_s[rr] && bj < run_j[rr])) { run_s[rr] = bs; run_j[rr] = bj; }
        }
    }

    if (tx == 0)
        #pragma unroll
        for (int rr = 0; rr < 4; ++rr) { dl[ty * 4 + rr] = run_s[rr]; jl[ty * 4 + rr] = run_j[rr]; }
    __syncthreads();

    const int row = tid >> 2;
    const int q   = tid & 3;
    {
        float p = 0.0f;
        const float* fr = &lds_f[row * F_LDF + q * 32];
        #pragma unroll
        for (int k8 = 0; k8 < 8; ++k8) {
            float4 v = *(const float4*)&fr[k8 * 4];
            p = fmaf(v.x, v.x, p); p = fmaf(v.y, v.y, p);
            p = fmaf(v.z, v.z, p); p = fmaf(v.w, v.w, p);
        }
        p += __shfl_xor(p, 1, 64);
        p += __shfl_xor(p, 2, 64);
        if (q == 0) dl[row] += p;
    }
    __syncthreads();

    if (tid < 16) {
        float s = dl[tid * 4] + dl[tid * 4 + 1] + dl[tid * 4 + 2] + dl[tid * 4 + 3];
        out[(size_t)rbk * 16 + tid] = 0.3125f * s;
    }
    {
        int j = jl[row];
        const float4* src = (const float4*)(W + (size_t)j * DIM + q * 32);
        float4* dst = (float4*)(out + 8192 + ((size_t)(rbk * F_BM + row)) * DIM + q * 32);
        #pragma unroll
        for (int k8 = 0; k8 < 8; ++k8) dst[k8] = src[k8];
    }
}

extern "C" void kernel_launch(void* const* d_in, const int* in_sizes, int n_in,
                              void* d_out, int out_size, void* d_ws, size_t ws_size,
                              hipStream_t stream) {
    const float* feature = (const float*)d_in[0];
    const float* W       = (const float*)d_in[1];
    float*       out     = (float*)d_out;

    const size_t need = 2u * 524288u + 8192u;  // whi + wlo + wsq
    if (ws_size >= need) {
        short* whi = (short*)d_ws;
        short* wlo = whi + 262144;
        float* wsq = (float*)((char*)d_ws + 1048576);
        vq_prep<<<32, 256, 0, stream>>>(W, whi, wlo, wsq);
        vq_mfma<<<256, 256, 0, stream>>>(feature, W, whi, wlo, wsq, out);
    } else {
        float* wsq = (float*)d_ws;
        wsq_kernel<<<512, 256, 0, stream>>>(W, wsq);
        vq_main<<<512, 256, 0, stream>>>(feature, W, wsq, out);
    }
}

// Round 11
// 218.603 us; speedup vs baseline: 1.6380x; 1.0056x over previous
//
#include <hip/hip_runtime.h>
#include <float.h>

// VQ-VAE nearest-codeword + loss, bf16x2-emulated fp32 GEMM on MFMA.
// feature: [8192, 512] fp32 -> rows f: [32768, 128]
// W: [2048, 128] fp32
// d_out: loss[8192] fp32, then out[32768*128] fp32
// R5: 8-wave blocks (code-split waves), 3 independent acc chains, parallel prep.
// (R11 = R5 resubmitted verbatim: R5-R10 never ran — GPU acquisition timeouts.)

#define NROWS 32768
#define DIM   128
#define NCODE 2048
#define BM    128            // rows per block  -> grid 256 = 1 block/CU
#define CB    128            // codes per main-loop iteration
#define NITER (NCODE / CB)   // 16
#define TAU   0.02f          // rescore threshold (error bound ~2e-3)

typedef __attribute__((ext_vector_type(8))) short short8v;  // 8 bf16 (4 VGPR)
typedef __attribute__((ext_vector_type(4))) float f32x4;

static __device__ __forceinline__ unsigned short f2bf_rne(float x) {
    unsigned u = __float_as_uint(x);
    unsigned r = u + 0x7FFFu + ((u >> 16) & 1u);
    return (unsigned short)(r >> 16);
}
static __device__ __forceinline__ float bf2f(unsigned short h) {
    return __uint_as_float(((unsigned)h) << 16);
}

// ---------------- prep: W fp32 -> frag-major bf16 hi/lo + wsq ----------------
// ws layout (shorts): whi[tile][kc][gg][c][8], strides tile:2048 kc:512 gg:128 c:8
// value = bf16(W[tile*16+c][kc*32+gg*8+e])
// One thread per (code, 8-dim group): 32768 threads = 128 blocks.
__global__ __launch_bounds__(256)
void vq_prep(const float* __restrict__ W, short* __restrict__ whi,
             short* __restrict__ wlo, float* __restrict__ wsq) {
    const int t    = blockIdx.x * 256 + threadIdx.x;  // 0..32767
    const int code = t >> 4;
    const int g    = t & 15;           // 8-dim group 0..15
    const float* src = W + (size_t)code * DIM + g * 8;

    float4 u0 = *(const float4*)(src);
    float4 u1 = *(const float4*)(src + 4);
    float xs[8] = { u0.x, u0.y, u0.z, u0.w, u1.x, u1.y, u1.z, u1.w };

    short8v hi, lo;
    float p = 0.0f;
    #pragma unroll
    for (int e = 0; e < 8; ++e) {
        unsigned short hb = f2bf_rne(xs[e]);
        float rem = xs[e] - bf2f(hb);
        unsigned short lb = f2bf_rne(rem);
        hi[e] = (short)hb; lo[e] = (short)lb;
        p = fmaf(xs[e], xs[e], p);
    }
    // reduce p over the 16 g-lanes of this code (g = low 4 bits of lane)
    p += __shfl_xor(p, 1, 64);
    p += __shfl_xor(p, 2, 64);
    p += __shfl_xor(p, 4, 64);
    p += __shfl_xor(p, 8, 64);
    if (g == 0) wsq[code] = p;

    const int tile = code >> 4;
    const int c    = code & 15;
    const int kc   = g >> 2;
    const int gg   = g & 3;
    const size_t off = (size_t)tile * 2048 + (size_t)kc * 512 + (size_t)gg * 128 + (size_t)c * 8;
    *(short8v*)(whi + off) = hi;
    *(short8v*)(wlo + off) = lo;
}

// ---------------- main MFMA kernel ----------------
// 512 threads = 8 waves. Wave w: rows rg=w&3 (32 rows, rf=2), code-half h=w>>2
// (tiles h*4..h*4+3 of each 128-code chunk). 1 block/CU, 2 waves/SIMD.
__global__ __launch_bounds__(512, 2)
void vq_mfma(const float* __restrict__ feature, const float* __restrict__ W,
             const short* __restrict__ whi, const short* __restrict__ wlo,
             const float* __restrict__ wsqg, float* __restrict__ out) {
    __shared__ short lds_w[2][2][16384];   // [buf][hi/lo][32KB of shorts] = 128KB
    __shared__ float wsq_l[NCODE];         // 8KB
    __shared__ float hs1[2][BM], hs2[2][BM];
    __shared__ int   hj[2][BM];
    __shared__ float dist_l[BM];
    __shared__ int   j_l[BM];
    __shared__ float fsq_l[BM];
    __shared__ int   flags[132];           // [0]=count, then row list
    __shared__ float frow[DIM];
    __shared__ float rbest[8];
    __shared__ int   rbj[8];

    const int tid  = threadIdx.x;
    const int lane = tid & 63;
    const int w    = tid >> 6;     // wave 0..7
    const int rg   = w & 3;        // row group (32 rows)
    const int h    = w >> 2;       // code half
    const int c    = lane & 15;    // col / code-local
    const int g    = lane >> 4;    // k-group / acc-row-group
    const int rb   = blockIdx.x;   // 256 blocks of 128 rows

    if (tid == 0) flags[0] = 0;

    short8v stg_h[4], stg_l[4];

    // ---- prologue: issue loads for cb=0 (chunk = 16384 shorts hi + 16384 lo) ----
    {
        const short8v* sh = (const short8v*)(whi + (size_t)tid * 8);
        const short8v* sl = (const short8v*)(wlo + (size_t)tid * 8);
        #pragma unroll
        for (int i = 0; i < 4; ++i) { stg_h[i] = sh[i * 512]; stg_l[i] = sl[i * 512]; }
    }

    // stage wsq to LDS (2048 floats / 512 threads = 4 each)
    {
        float4 a = *(const float4*)(wsqg + tid * 4);
        *(float4*)&wsq_l[tid * 4] = a;
    }

    // ---- load f rows, split to bf16 hi/lo A-fragments (in registers) ----
    // A-frag layout (16x16x32): lane holds A[row=c][k = kc*32 + g*8 + e]
    short8v Ahi[2][4], Alo[2][4];
    #pragma unroll
    for (int rf = 0; rf < 2; ++rf) {
        const int row = rb * BM + rg * 32 + rf * 16 + c;
        const float* fp = feature + (size_t)row * DIM + g * 8;
        float fs = 0.0f;
        #pragma unroll
        for (int kc = 0; kc < 4; ++kc) {
            float4 u0 = *(const float4*)(fp + kc * 32);
            float4 u1 = *(const float4*)(fp + kc * 32 + 4);
            float xs[8] = { u0.x, u0.y, u0.z, u0.w, u1.x, u1.y, u1.z, u1.w };
            short8v hi, lo;
            #pragma unroll
            for (int e = 0; e < 8; ++e) {
                unsigned short hb = f2bf_rne(xs[e]);
                float rem = xs[e] - bf2f(hb);
                unsigned short lb = f2bf_rne(rem);
                hi[e] = (short)hb; lo[e] = (short)lb;
                fs = fmaf(xs[e], xs[e], fs);
            }
            Ahi[rf][kc] = hi; Alo[rf][kc] = lo;
        }
        // combine partial f_sq over the 4 g-groups of this row (half 0 writes)
        fs += __shfl_xor(fs, 16, 64);
        fs += __shfl_xor(fs, 32, 64);
        if (h == 0 && g == 0) fsq_l[rg * 32 + rf * 16 + c] = fs;
    }

    // ---- prologue: write cb=0 into buf 0 ----
    #pragma unroll
    for (int i = 0; i < 4; ++i)
        *(short8v*)&lds_w[0][0][tid * 8 + i * 4096] = stg_h[i];
    #pragma unroll
    for (int i = 0; i < 4; ++i)
        *(short8v*)&lds_w[0][1][tid * 8 + i * 4096] = stg_l[i];

    // top-2 trackers per lane: rows (g*4+q) of each row-frag, code c of each tile
    float s1[2][4], s2[2][4];
    int   j1[2][4];
    #pragma unroll
    for (int rf = 0; rf < 2; ++rf)
        #pragma unroll
        for (int q = 0; q < 4; ++q) { s1[rf][q] = FLT_MAX; s2[rf][q] = FLT_MAX; j1[rf][q] = NCODE; }

    __syncthreads();  // buf0 + wsq_l ready

    for (int cb = 0; cb < NITER; ++cb) {
        const int  buf = cb & 1;
        const bool pre = (cb + 1 < NITER);
        if (pre) {  // issue next chunk's global loads early (hide under MFMA)
            const short8v* sh = (const short8v*)(whi + (size_t)(cb + 1) * 16384 + (size_t)tid * 8);
            const short8v* sl = (const short8v*)(wlo + (size_t)(cb + 1) * 16384 + (size_t)tid * 8);
            #pragma unroll
            for (int i = 0; i < 4; ++i) { stg_h[i] = sh[i * 512]; stg_l[i] = sl[i * 512]; }
        }

        const short* bh = &lds_w[buf][0][0];
        const short* bl = &lds_w[buf][1][0];

        #pragma unroll
        for (int tl = 0; tl < 4; ++tl) {
            const int t = h * 4 + tl;   // this wave's tile within the chunk
            short8v Bh[4], Bl[4];
            #pragma unroll
            for (int kc = 0; kc < 4; ++kc) {
                Bh[kc] = *(const short8v*)(bh + t * 2048 + kc * 512 + lane * 8);
                Bl[kc] = *(const short8v*)(bl + t * 2048 + kc * 512 + lane * 8);
            }
            const int   codebase = cb * CB + t * 16 + c;
            const float wq       = wsq_l[codebase];

            #pragma unroll
            for (int rf = 0; rf < 2; ++rf) {
                // 3 independent 4-deep chains (hh, hl, lh) -> ILP
                f32x4 ahh = {0.f, 0.f, 0.f, 0.f};
                f32x4 ahl = {0.f, 0.f, 0.f, 0.f};
                f32x4 alh = {0.f, 0.f, 0.f, 0.f};
                #pragma unroll
                for (int kc = 0; kc < 4; ++kc) {
                    ahh = __builtin_amdgcn_mfma_f32_16x16x32_bf16(Ahi[rf][kc], Bh[kc], ahh, 0, 0, 0);
                    ahl = __builtin_amdgcn_mfma_f32_16x16x32_bf16(Ahi[rf][kc], Bl[kc], ahl, 0, 0, 0);
                    alh = __builtin_amdgcn_mfma_f32_16x16x32_bf16(Alo[rf][kc], Bh[kc], alh, 0, 0, 0);
                }
                #pragma unroll
                for (int q = 0; q < 4; ++q) {
                    float dot = ahh[q] + ahl[q] + alh[q];
                    float s   = fmaf(-2.0f, dot, wq);
                    bool  lt  = s < s1[rf][q];
                    s2[rf][q] = fminf(s2[rf][q], lt ? s1[rf][q] : s);
                    j1[rf][q] = lt ? codebase : j1[rf][q];
                    s1[rf][q] = lt ? s : s1[rf][q];
                }
            }
        }

        if (pre) {  // write next chunk into the other buffer
            #pragma unroll
            for (int i = 0; i < 4; ++i)
                *(short8v*)&lds_w[buf ^ 1][0][tid * 8 + i * 4096] = stg_h[i];
            #pragma unroll
            for (int i = 0; i < 4; ++i)
                *(short8v*)&lds_w[buf ^ 1][1][tid * 8 + i * 4096] = stg_l[i];
        }
        __syncthreads();
    }

    // ---- cross-lane top-2 merge over the 16 code-lanes (xor 1,2,4,8 flip c) ----
    #pragma unroll
    for (int rf = 0; rf < 2; ++rf) {
        #pragma unroll
        for (int q = 0; q < 4; ++q) {
            float a1 = s1[rf][q]; int aj = j1[rf][q]; float a2 = s2[rf][q];
            #pragma unroll
            for (int m = 1; m < 16; m <<= 1) {
                float b1 = __shfl_xor(a1, m, 64);
                int   bj = __shfl_xor(aj, m, 64);
                float b2 = __shfl_xor(a2, m, 64);
                bool swap = (b1 < a1) || (b1 == a1 && bj < aj);
                float other1 = swap ? a1 : b1;
                a2 = fminf(fminf(a2, b2), other1);
                a1 = swap ? b1 : a1;
                aj = swap ? bj : aj;
            }
            if (c == 0) {
                const int row = rg * 32 + rf * 16 + g * 4 + q;
                hs1[h][row] = a1;
                hs2[h][row] = a2;
                hj[h][row]  = aj;
            }
        }
    }
    __syncthreads();

    // ---- merge the two code halves per row; flag near-ties ----
    if (tid < BM) {
        const int row = tid;
        float a1 = hs1[0][row], a2 = hs2[0][row]; int aj = hj[0][row];
        float b1 = hs1[1][row], b2 = hs2[1][row]; int bj = hj[1][row];
        bool swap = (b1 < a1) || (b1 == a1 && bj < aj);
        float other1 = swap ? a1 : b1;
        float m2 = fminf(fminf(a2, b2), other1);
        float m1 = swap ? b1 : a1;
        int   mj = swap ? bj : aj;
        dist_l[row] = m1;
        j_l[row]    = mj;
        if (m2 - m1 < TAU) {
            int idx = atomicAdd(&flags[0], 1);
            flags[1 + idx] = row;
        }
    }
    __syncthreads();

    // ---- exact fp32 rescore for flagged rows (rare) ----
    const int nf = flags[0];
    for (int i = 0; i < nf; ++i) {
        const int row = flags[1 + i];
        if (tid < 32) {
            float4 v = *(const float4*)(feature + ((size_t)(rb * BM + row)) * DIM + tid * 4);
            *(float4*)&frow[tid * 4] = v;
        }
        __syncthreads();
        float best = FLT_MAX; int bj = NCODE;
        #pragma unroll 1
        for (int cc = 0; cc < 4; ++cc) {
            const int code = tid * 4 + cc;
            const float* wp = W + (size_t)code * DIM;
            float d = 0.0f;
            #pragma unroll
            for (int k = 0; k < DIM; k += 4) {
                float4 wv = *(const float4*)(wp + k);
                d = fmaf(wv.x, frow[k],     d);
                d = fmaf(wv.y, frow[k + 1], d);
                d = fmaf(wv.z, frow[k + 2], d);
                d = fmaf(wv.w, frow[k + 3], d);
            }
            float s = wsq_l[code] - 2.0f * d;
            if (s < best) { best = s; bj = code; }
        }
        #pragma unroll
        for (int m = 1; m < 64; m <<= 1) {
            float ob = __shfl_xor(best, m, 64);
            int   oj = __shfl_xor(bj, m, 64);
            if (ob < best || (ob == best && oj < bj)) { best = ob; bj = oj; }
        }
        if (lane == 0) { rbest[w] = best; rbj[w] = bj; }
        __syncthreads();
        if (tid == 0) {
            float bb = rbest[0]; int jj = rbj[0];
            #pragma unroll
            for (int ww = 1; ww < 8; ++ww) {
                if (rbest[ww] < bb || (rbest[ww] == bb && rbj[ww] < jj)) { bb = rbest[ww]; jj = rbj[ww]; }
            }
            dist_l[row] = bb; j_l[row] = jj;
        }
        __syncthreads();
    }

    // ---- loss: 32 batch rows per block ----
    if (tid < 32) {
        float s = 0.0f;
        #pragma unroll
        for (int sl = 0; sl < 4; ++sl) {
            int r = tid * 4 + sl;
            s += dist_l[r] + fsq_l[r];
        }
        out[(size_t)rb * 32 + tid] = 0.3125f * s;  // 1.25 / 4
    }

    // ---- gather out rows: 4 threads per row ----
    {
        const int row = tid >> 2;     // 0..127
        const int q   = tid & 3;
        const int j   = j_l[row];
        const float4* src = (const float4*)(W + (size_t)j * DIM + q * 32);
        float4* dst = (float4*)(out + 8192 + ((size_t)(rb * BM + row)) * DIM + q * 32);
        #pragma unroll
        for (int k8 = 0; k8 < 8; ++k8) dst[k8] = src[k8];
    }
}

// ---------------- fallback (round-1 fp32 VALU path, used if ws too small) ----------------
#define F_BM  64
#define F_BN  128
#define F_BK  32
#define F_LDF 132
#define F_LDW 36

__global__ __launch_bounds__(256)
void wsq_kernel(const float* __restrict__ W, float* __restrict__ wsq) {
    const int wv   = threadIdx.x >> 6;
    const int lane = threadIdx.x & 63;
    const int code = blockIdx.x * 4 + wv;
    float2 v = *(const float2*)(W + (size_t)code * DIM + lane * 2);
    float p = v.x * v.x + v.y * v.y;
    #pragma unroll
    for (int m = 1; m < 64; m <<= 1) p += __shfl_xor(p, m, 64);
    if (lane == 0) wsq[code] = p;
}

__global__ __launch_bounds__(256, 3)
void vq_main(const float* __restrict__ feature, const float* __restrict__ W,
             const float* __restrict__ wsq, float* __restrict__ out) {
    __shared__ float lds_f[F_BM * F_LDF];
    __shared__ float lds_w[F_BN * F_LDW];
    __shared__ float dl[F_BM];
    __shared__ int   jl[F_BM];

    const int tid = threadIdx.x;
    const int tx  = tid & 15;
    const int ty  = tid >> 4;
    const int rbk = blockIdx.x;

    {
        const float* fbase = feature + (size_t)rbk * F_BM * DIM;
        #pragma unroll
        for (int t = 0; t < 8; ++t) {
            int f4 = tid + t * 256;
            int row = f4 >> 5, dcol = (f4 & 31) << 2;
            float4 v = *(const float4*)(fbase + (size_t)f4 * 4);
            *(float4*)&lds_f[row * F_LDF + dcol] = v;
        }
    }

    float run_s[4]; int run_j[4];
    #pragma unroll
    for (int rr = 0; rr < 4; ++rr) { run_s[rr] = 3.4e38f; run_j[rr] = 0; }

    for (int cb = 0; cb < NCODE / F_BN; ++cb) {
        float acc[4][8];
        #pragma unroll
        for (int rr = 0; rr < 4; ++rr)
            #pragma unroll
            for (int cc = 0; cc < 8; ++cc) acc[rr][cc] = 0.0f;

        for (int dc = 0; dc < DIM / F_BK; ++dc) {
            __syncthreads();
            #pragma unroll
            for (int t = 0; t < 4; ++t) {
                int f4 = tid + t * 256;
                int cx = f4 >> 3, dd4 = (f4 & 7) << 2;
                float4 v = *(const float4*)(W + ((size_t)(cb * F_BN + cx)) * DIM + dc * F_BK + dd4);
                *(float4*)&lds_w[cx * F_LDW + dd4] = v;
            }
            __syncthreads();

            #pragma unroll
            for (int dd = 0; dd < F_BK; dd += 4) {
                float4 fa[4];
                #pragma unroll
                for (int rr = 0; rr < 4; ++rr)
                    fa[rr] = *(const float4*)&lds_f[(ty * 4 + rr) * F_LDF + dc * F_BK + dd];
                float4 wb[8];
                #pragma unroll
                for (int cc = 0; cc < 8; ++cc)
                    wb[cc] = *(const float4*)&lds_w[(cc * 16 + tx) * F_LDW + dd];
                #pragma unroll
                for (int rr = 0; rr < 4; ++rr)
                    #pragma unroll
                    for (int cc = 0; cc < 8; ++cc) {
                        float a = acc[rr][cc];
                        a = fmaf(fa[rr].x, wb[cc].x, a);
                        a = fmaf(fa[rr].y, wb[cc].y, a);
                        a = fmaf(fa[rr].z, wb[cc].z, a);
                        a = fmaf(fa[rr].w, wb[cc].w, a);
                        acc[rr][cc] = a;
                    }
            }
        }

        float ws8[8];
        #pragma unroll
        for (int cc = 0; cc < 8; ++cc) ws8[cc] = wsq[cb * F_BN + cc * 16 + tx];

        #pragma unroll
        for (int rr = 0; rr < 4; ++rr) {
            float bs = 3.4e38f; int bj = 0x7fffffff;
            #pragma unroll
            for (int cc = 0; cc < 8; ++cc) {
                int code = cb * F_BN + cc * 16 + tx;
                float s = ws8[cc] - 2.0f * acc[rr][cc];
                if (s < bs) { bs = s; bj = code; }
            }
            #pragma unroll
            for (int m = 1; m < 16; m <<= 1) {
                float os = __shfl_xor(bs, m, 64);
                int   oj = __shfl_xor(bj, m, 64);
                if (os < bs || (os == bs && oj < bj)) { bs = os; bj = oj; }
            }
            if (bs < run_s[rr] || (bs == run_s[rr] && bj < run_j[rr])) { run_s[rr] = bs; run_j[rr] = bj; }
        }
    }

    if (tx == 0)
        #pragma unroll
        for (int rr = 0; rr < 4; ++rr) { dl[ty * 4 + rr] = run_s[rr]; jl[ty * 4 + rr] = run_j[rr]; }
    __syncthreads();

    const int row = tid >> 2;
    const int q   = tid & 3;
    {
        float p = 0.0f;
        const float* fr = &lds_f[row * F_LDF + q * 32];
        #pragma unroll
        for (int k8 = 0; k8 < 8; ++k8) {
            float4 v = *(const float4*)&fr[k8 * 4];
            p = fmaf(v.x, v.x, p); p = fmaf(v.y, v.y, p);
            p = fmaf(v.z, v.z, p); p = fmaf(v.w, v.w, p);
        }
        p += __shfl_xor(p, 1, 64);
        p += __shfl_xor(p, 2, 64);
        if (q == 0) dl[row] += p;
    }
    __syncthreads();

    if (tid < 16) {
        float s = dl[tid * 4] + dl[tid * 4 + 1] + dl[tid * 4 + 2] + dl[tid * 4 + 3];
        out[(size_t)rbk * 16 + tid] = 0.3125f * s;
    }
    {
        int j = jl[row];
        const float4* src = (const float4*)(W + (size_t)j * DIM + q * 32);
        float4* dst = (float4*)(out + 8192 + ((size_t)(rbk * F_BM + row)) * DIM + q * 32);
        #pragma unroll
        for (int k8 = 0; k8 < 8; ++k8) dst[k8] = src[k8];
    }
}

extern "C" void kernel_launch(void* const* d_in, const int* in_sizes, int n_in,
                              void* d_out, int out_size, void* d_ws, size_t ws_size,
                              hipStream_t stream) {
    const float* feature = (const float*)d_in[0];
    const float* W       = (const float*)d_in[1];
    float*       out     = (float*)d_out;

    const size_t need = 2u * 524288u + 8192u;  // whi + wlo + wsq
    if (ws_size >= need) {
        short* whi = (short*)d_ws;
        short* wlo = whi + 262144;
        float* wsq = (float*)((char*)d_ws + 1048576);
        vq_prep<<<128, 256, 0, stream>>>(W, whi, wlo, wsq);
        vq_mfma<<<256, 512, 0, stream>>>(feature, W, whi, wlo, wsq, out);
    } else {
        float* wsq = (float*)d_ws;
        wsq_kernel<<<512, 256, 0, stream>>>(W, wsq);
        vq_main<<<512, 256, 0, stream>>>(feature, W, wsq, out);
    }
}